// Round 2
// baseline (253.844 us; speedup 1.0000x reference)
//
#include <hip/hip_runtime.h>
#include <cstdint>

// Problem constants
#define BB 4
#define TT 2048      // TQ == TK
#define DD 512
#define HH 8
#define DH 64
#define NT (TT / 64) // KV tiles of 64

using bf16x8 = __attribute__((ext_vector_type(8))) __bf16;
using f32x4  = __attribute__((ext_vector_type(4))) float;
using f32x16 = __attribute__((ext_vector_type(16))) float;
using us8    = __attribute__((ext_vector_type(8))) unsigned short;
using us4    = __attribute__((ext_vector_type(4))) unsigned short;
using u32x2  = __attribute__((ext_vector_type(2))) unsigned int;

typedef const __attribute__((address_space(1))) unsigned int* as1cp;
typedef __attribute__((address_space(3))) unsigned int* as3p;

__device__ __forceinline__ void gload16(const void* g, void* l) {
  __builtin_amdgcn_global_load_lds((as1cp)(uintptr_t)g,
                                   (as3p)(unsigned int)(uintptr_t)l, 16, 0, 0);
}

__device__ __forceinline__ unsigned short f2bf(float x) {
  unsigned int u = __float_as_uint(x);
  u += 0x7fffu + ((u >> 16) & 1u);
  return (unsigned short)(u >> 16);
}
__device__ __forceinline__ float bf2f(unsigned short u) {
  return __uint_as_float(((unsigned int)u) << 16);
}
__device__ __forceinline__ f32x4 MFMA(bf16x8 a, bf16x8 b, f32x4 c) {
  return __builtin_amdgcn_mfma_f32_16x16x32_bf16(a, b, c, 0, 0, 0);
}
__device__ __forceinline__ f32x16 MFMA32(bf16x8 a, bf16x8 b, f32x16 c) {
  return __builtin_amdgcn_mfma_f32_32x32x16_bf16(a, b, c, 0, 0, 0);
}
// v_cvt_pk_bf16_f32: dst[15:0]=bf16(lo), dst[31:16]=bf16(hi)
__device__ __forceinline__ unsigned int cvtpk(float lo, float hi) {
  unsigned int r;
  asm("v_cvt_pk_bf16_f32 %0, %1, %2" : "=v"(r) : "v"(lo), "v"(hi));
  return r;
}

// ---------------- 1. convert inputs to bf16 ----------------
__global__ __launch_bounds__(256) void cvt_inputs(const float4* __restrict__ q,
                                                  const float4* __restrict__ k,
                                                  us4* __restrict__ qb,
                                                  us4* __restrict__ kb) {
  size_t i = (size_t)blockIdx.x * 256 + threadIdx.x;
  float4 a = q[i];
  us4 o; o[0] = f2bf(a.x); o[1] = f2bf(a.y); o[2] = f2bf(a.z); o[3] = f2bf(a.w);
  qb[i] = o;
  float4 b = k[i];
  us4 p; p[0] = f2bf(b.x); p[1] = f2bf(b.y); p[2] = f2bf(b.z); p[3] = f2bf(b.w);
  kb[i] = p;
}

// ---------------- 2. weight transpose + convert ----------------
__global__ __launch_bounds__(256) void cvt_w(const float* __restrict__ Wq,
                                             const float* __restrict__ Wk,
                                             const float* __restrict__ Wv,
                                             unsigned short* __restrict__ Wt) {
  __shared__ float tile[32][33];
  int z = blockIdx.z;
  const float* W = (z == 0) ? Wq : (z == 1) ? Wk : Wv;
  int k0 = blockIdx.x * 32, n0 = blockIdx.y * 32;
  int r = threadIdx.x >> 5, c = threadIdx.x & 31;
#pragma unroll
  for (int p = 0; p < 4; ++p)
    tile[r + p * 8][c] = W[(size_t)(k0 + r + p * 8) * DD + n0 + c];
  __syncthreads();
  unsigned short* o = Wt + (size_t)z * DD * DD;
#pragma unroll
  for (int p = 0; p < 4; ++p)
    o[(size_t)(n0 + r + p * 8) * DD + k0 + c] = f2bf(tile[c][r + p * 8]);
}

// ---------------- 3. projection GEMM: out = relu(A @ W + b) [* 0.125 for Q] ----------------
__global__ __launch_bounds__(256) void gemm_proj(const unsigned short* __restrict__ qb,
                                                 const unsigned short* __restrict__ kb,
                                                 const unsigned short* __restrict__ Wt,
                                                 const float* __restrict__ bq,
                                                 const float* __restrict__ bk,
                                                 const float* __restrict__ bv,
                                                 unsigned short* __restrict__ Qp,
                                                 unsigned short* __restrict__ Kp,
                                                 unsigned short* __restrict__ Vp) {
  int z = blockIdx.z;
  const unsigned short* A  = (z == 0) ? qb : kb;
  const unsigned short* Bt = Wt + (size_t)z * DD * DD;
  const float* bias = (z == 0) ? bq : (z == 1) ? bk : bv;
  unsigned short* out = (z == 0) ? Qp : (z == 1) ? Kp : Vp;
  const float osc = (z == 0) ? 0.125f : 1.0f;   // fold 1/sqrt(dh) into Q

  __shared__ __align__(16) unsigned short As[128 * 32];
  __shared__ __align__(16) unsigned short Bs[128 * 32];

  int mb = blockIdx.x * 128, nb = blockIdx.y * 128;
  int w = threadIdx.x >> 6, lane = threadIdx.x & 63;
  int l15 = lane & 15, lg = lane >> 4;
  int wr = (w >> 1) * 64, wc = (w & 1) * 64;

  f32x4 acc[4][4] = {};

  for (int kt = 0; kt < DD / 32; ++kt) {
    int kk = kt * 32;
    int t = threadIdx.x;
#pragma unroll
    for (int it = 0; it < 2; ++it) {
      int c = t + it * 256;
      gload16(A  + (size_t)(mb + (c >> 2)) * DD + kk + (c & 3) * 8, As + c * 8);
      gload16(Bt + (size_t)(nb + (c >> 2)) * DD + kk + (c & 3) * 8, Bs + c * 8);
    }
    __syncthreads();
    bf16x8 af[4], bf[4];
#pragma unroll
    for (int m = 0; m < 4; ++m)
      af[m] = *(const bf16x8*)&As[(wr + m * 16 + l15) * 32 + lg * 8];
#pragma unroll
    for (int n = 0; n < 4; ++n)
      bf[n] = *(const bf16x8*)&Bs[(wc + n * 16 + l15) * 32 + lg * 8];
#pragma unroll
    for (int m = 0; m < 4; ++m)
#pragma unroll
      for (int n = 0; n < 4; ++n)
        acc[m][n] = MFMA(af[m], bf[n], acc[m][n]);
    __syncthreads();
  }

#pragma unroll
  for (int m = 0; m < 4; ++m)
#pragma unroll
    for (int n = 0; n < 4; ++n)
#pragma unroll
      for (int i = 0; i < 4; ++i) {
        int row = mb + wr + m * 16 + lg * 4 + i;
        int col = nb + wc + n * 16 + l15;
        float v = acc[m][n][i] + bias[col];
        out[(size_t)row * DD + col] = f2bf(fmaxf(v, 0.f) * osc);
      }
}

// ---------------- 4. V transpose: Vp[B*TK, D] -> Vt[B, D, TK] ----------------
__global__ __launch_bounds__(256) void transpose_v(const unsigned short* __restrict__ Vp,
                                                   unsigned short* __restrict__ Vt) {
  __shared__ unsigned short tile[64][72];
  int b = blockIdx.z, k0 = blockIdx.x * 64, d0 = blockIdx.y * 64;
  int t = threadIdx.x;
  int r = t >> 3, c8 = (t & 7) * 8;
#pragma unroll
  for (int p = 0; p < 2; ++p) {
    int row = r + p * 32;
    us8 v = *(const us8*)&Vp[(size_t)(b * TT + k0 + row) * DD + d0 + c8];
#pragma unroll
    for (int j = 0; j < 8; ++j) tile[row][c8 + j] = v[j];
  }
  __syncthreads();
#pragma unroll
  for (int p = 0; p < 2; ++p) {
    int dr = r + p * 32;
    us8 o;
#pragma unroll
    for (int j = 0; j < 8; ++j) o[j] = tile[c8 + j][dr];
    *(us8*)&Vt[((size_t)b * DD + d0 + dr) * TT + k0 + c8] = o;
  }
}

// ---------------- 5. masks: qmask float [B*H][TT]; kmask as bitwords uint2 per tile-64 ----------------
__global__ __launch_bounds__(256) void mask_kernel(const unsigned short* __restrict__ Qp,
                                                   const unsigned short* __restrict__ Kp,
                                                   float* __restrict__ qmask,
                                                   uint2* __restrict__ kbits) {
  int id = blockIdx.x * 4 + (threadIdx.x >> 6);   // [0, 2048) waves
  int lane = threadIdx.x & 63;
  int side = id >> 10;            // 0 = Q, 1 = K
  int rem = id & 1023;
  int bh = rem >> 5, tile = rem & 31;
  int b = bh >> 3, h = bh & 7;
  const unsigned short* src =
      (side ? Kp : Qp) + ((size_t)(b * TT + tile * 64 + lane)) * DD + h * DH;
  float s = 0.f;
#pragma unroll
  for (int j = 0; j < 64; j += 8) {
    us8 v = *(const us8*)(src + j);
#pragma unroll
    for (int e = 0; e < 8; ++e) s += bf2f(v[e]);
  }
  if (side == 0) {
    qmask[(size_t)bh * TT + tile * 64 + lane] = (s > 0.f) ? 1.f : 0.f;
  } else {
    unsigned long long mb = __ballot(s > 0.f);
    if (lane == 0)
      kbits[bh * NT + tile] = make_uint2((unsigned int)mb, (unsigned int)(mb >> 32));
  }
}

// ---------------- 6. flash attention (swapped-operand, in-register softmax) ----------------
// Per wave: 32 q-rows. S^T = mfma(Kfrag, Qfrag) -> lane holds P[.][qrow=lane&31].
// O^T = mfma(Vtfrag, Pfrag) -> col stays qrow: m/l/alpha/qmask all lane-local.
#define PV_SLOT(SS, base, ks)                                               \
  {                                                                         \
    unsigned int w0_ = cvtpk(SS[(base) + 0], SS[(base) + 1]);               \
    unsigned int w1_ = cvtpk(SS[(base) + 2], SS[(base) + 3]);               \
    unsigned int w2_ = cvtpk(SS[(base) + 4], SS[(base) + 5]);               \
    unsigned int w3_ = cvtpk(SS[(base) + 6], SS[(base) + 7]);               \
    u32x2 r20_ = __builtin_amdgcn_permlane32_swap(w2_, w0_, false, false);  \
    u32x2 r31_ = __builtin_amdgcn_permlane32_swap(w3_, w1_, false, false);  \
    union { unsigned int u[4]; bf16x8 v; } pa_;                             \
    pa_.u[0] = r20_[1]; pa_.u[1] = r31_[1];                                 \
    pa_.u[2] = r20_[0]; pa_.u[3] = r31_[0];                                 \
    oat0 = MFMA32(vf0[(ks)], pa_.v, oat0);                                  \
    oat1 = MFMA32(vf1[(ks)], pa_.v, oat1);                                  \
  }

__device__ __forceinline__ void attn_body(
    const bf16x8 (&KC0)[4], const bf16x8 (&KC1)[4],
    bf16x8 (&KN0)[4], bf16x8 (&KN1)[4],
    const bf16x8 (&qf)[4],
    f32x16& oat0, f32x16& oat1, float& m_i, float& l_i,
    int t, const unsigned short* __restrict__ kbase,
    const unsigned short* __restrict__ vbase,
    const uint2* __restrict__ kb_ptr, int h2) {
  uint2 kw = kb_ptr[t];

  // V loads for this tile (used after softmax -> latency hidden)
  const unsigned short* vp = vbase + t * 64;
  bf16x8 vf0[4], vf1[4];
#pragma unroll
  for (int ks = 0; ks < 4; ++ks) {
    vf0[ks] = *(const bf16x8*)(vp + ks * 16);
    vf1[ks] = *(const bf16x8*)(vp + 32 * TT + ks * 16);
  }

  // S^T = K . Q^T : s0 covers kpos 0..31, s1 kpos 32..63 of this tile
  f32x16 s0 = {}, s1 = {};
#pragma unroll
  for (int kd = 0; kd < 4; ++kd) s0 = MFMA32(KC0[kd], qf[kd], s0);
#pragma unroll
  for (int kd = 0; kd < 4; ++kd) s1 = MFMA32(KC1[kd], qf[kd], s1);

  // prefetch next K tile into the other buffer
  {
    int tp = (t + 1 < NT) ? t + 1 : NT - 1;
    const unsigned short* kp = kbase + (size_t)tp * (64 * DD);
#pragma unroll
    for (int kd = 0; kd < 4; ++kd) {
      KN0[kd] = *(const bf16x8*)(kp + kd * 16);
      KN1[kd] = *(const bf16x8*)(kp + 32 * DD + kd * 16);
    }
  }

  // key mask (fast path: all ones)
  if ((kw.x & kw.y) != 0xffffffffu) {
    unsigned int w0s = kw.x >> (h2 * 4), w1s = kw.y >> (h2 * 4);
#pragma unroll
    for (int r = 0; r < 16; ++r) {
      int bi = (r & 3) + 8 * (r >> 2);
      if (!((w0s >> bi) & 1)) s0[r] = -1e30f;
      if (!((w1s >> bi) & 1)) s1[r] = -1e30f;
    }
  }

  // row max (own 32) + cross-half combine
  float x0 = fmaxf(fmaxf(fmaxf(s0[0], s0[1]), fmaxf(s0[2], s0[3])),
                   fmaxf(fmaxf(s0[4], s0[5]), fmaxf(s0[6], s0[7])));
  float x1 = fmaxf(fmaxf(fmaxf(s0[8], s0[9]), fmaxf(s0[10], s0[11])),
                   fmaxf(fmaxf(s0[12], s0[13]), fmaxf(s0[14], s0[15])));
  float x2 = fmaxf(fmaxf(fmaxf(s1[0], s1[1]), fmaxf(s1[2], s1[3])),
                   fmaxf(fmaxf(s1[4], s1[5]), fmaxf(s1[6], s1[7])));
  float x3 = fmaxf(fmaxf(fmaxf(s1[8], s1[9]), fmaxf(s1[10], s1[11])),
                   fmaxf(fmaxf(s1[12], s1[13]), fmaxf(s1[14], s1[15])));
  float pm = fmaxf(fmaxf(x0, x1), fmaxf(x2, x3));
  u32x2 sw = __builtin_amdgcn_permlane32_swap(__float_as_uint(pm),
                                              __float_as_uint(pm), false, false);
  pm = fmaxf(__uint_as_float(sw[0]), __uint_as_float(sw[1]));

  // defer-max: rescale only when max grew by > 8 (exact math, f32 headroom)
  if (__any(pm > m_i + 8.f)) {
    float mn = fmaxf(m_i, pm);
    float al = __expf(m_i - mn);
    m_i = mn;
    l_i *= al;
#pragma unroll
    for (int r = 0; r < 16; ++r) { oat0[r] *= al; oat1[r] *= al; }
  }

  // p = exp(s - m), row sum
  float a0 = 0.f, a1 = 0.f, a2 = 0.f, a3 = 0.f;
#pragma unroll
  for (int r = 0; r < 8; ++r)  { float p = __expf(s0[r] - m_i); s0[r] = p; a0 += p; }
#pragma unroll
  for (int r = 8; r < 16; ++r) { float p = __expf(s0[r] - m_i); s0[r] = p; a1 += p; }
#pragma unroll
  for (int r = 0; r < 8; ++r)  { float p = __expf(s1[r] - m_i); s1[r] = p; a2 += p; }
#pragma unroll
  for (int r = 8; r < 16; ++r) { float p = __expf(s1[r] - m_i); s1[r] = p; a3 += p; }
  float rs = (a0 + a1) + (a2 + a3);
  u32x2 sr = __builtin_amdgcn_permlane32_swap(__float_as_uint(rs),
                                              __float_as_uint(rs), false, false);
  rs = __uint_as_float(sr[0]) + __uint_as_float(sr[1]);
  l_i += rs;

  // O^T += Vt . P : pack P to bf16 in-register (cvt_pk + permlane32_swap)
  PV_SLOT(s0, 0, 0)
  PV_SLOT(s0, 8, 1)
  PV_SLOT(s1, 0, 2)
  PV_SLOT(s1, 8, 3)
}

__global__ __launch_bounds__(256) void attn_kernel(
    const unsigned short* __restrict__ Qp,
    const unsigned short* __restrict__ Kp,
    const unsigned short* __restrict__ Vt,
    const uint2* __restrict__ kbits,
    const float* __restrict__ qmask,
    float* __restrict__ O) {
  const int w = threadIdx.x >> 6;
  const int lane = threadIdx.x & 63;
  const int l31 = lane & 31, h2 = lane >> 5;

  // XCD-bijective swizzle: 512 blocks -> each (b,h)'s 16 q-tiles on one XCD
  int flat = blockIdx.x;
  int wg = (flat & 7) * 64 + (flat >> 3);
  int qt = wg & 15, bh = wg >> 4;
  int h = bh & 7, b = bh >> 3;
  int q0 = qt * 128 + w * 32;

  const unsigned short* qbase =
      Qp + ((size_t)(b * TT + q0 + l31)) * DD + h * DH + h2 * 8;
  bf16x8 qf[4];
#pragma unroll
  for (int kd = 0; kd < 4; ++kd) qf[kd] = *(const bf16x8*)(qbase + kd * 16);

  const unsigned short* kbase =
      Kp + ((size_t)(b * TT + l31)) * DD + h * DH + h2 * 8;
  const unsigned short* vbase =
      Vt + ((size_t)(b * DD + h * DH + l31)) * TT + h2 * 8;
  const uint2* kb_ptr = kbits + (size_t)bh * NT;

  bf16x8 kA0[4], kA1[4], kB0[4], kB1[4];
#pragma unroll
  for (int kd = 0; kd < 4; ++kd) {
    kA0[kd] = *(const bf16x8*)(kbase + kd * 16);
    kA1[kd] = *(const bf16x8*)(kbase + 32 * DD + kd * 16);
  }

  f32x16 oat0 = {}, oat1 = {};
  float m_i = -1e30f, l_i = 0.f;

  for (int t = 0; t < NT; t += 2) {
    attn_body(kA0, kA1, kB0, kB1, qf, oat0, oat1, m_i, l_i, t, kbase, vbase, kb_ptr, h2);
    attn_body(kB0, kB1, kA0, kA1, qf, oat0, oat1, m_i, l_i, t + 1, kbase, vbase, kb_ptr, h2);
  }

  // epilogue: all lane-local. oat reg r -> d = (r&3) + 8*(r>>2) + 4*h2 (+32 for oat1)
  float qm = qmask[(size_t)bh * TT + q0 + l31];
  float sc = qm / l_i;
  float* ob = O + ((size_t)(b * TT + q0 + l31)) * DD + h * DH + h2 * 4;
#pragma unroll
  for (int qq = 0; qq < 4; ++qq) {
    float4 v0 = make_float4(oat0[4 * qq + 0] * sc, oat0[4 * qq + 1] * sc,
                            oat0[4 * qq + 2] * sc, oat0[4 * qq + 3] * sc);
    *(float4*)(ob + 8 * qq) = v0;
    float4 v1 = make_float4(oat1[4 * qq + 0] * sc, oat1[4 * qq + 1] * sc,
                            oat1[4 * qq + 2] * sc, oat1[4 * qq + 3] * sc);
    *(float4*)(ob + 32 + 8 * qq) = v1;
  }
}

// ---------------- 7. residual + LayerNorm ----------------
__global__ __launch_bounds__(256) void ln_kernel(const float* __restrict__ O,
                                                 const float* __restrict__ qin,
                                                 const float* __restrict__ gamma,
                                                 const float* __restrict__ beta,
                                                 float* __restrict__ out) {
  int row = blockIdx.x * 4 + (threadIdx.x >> 6);
  int lane = threadIdx.x & 63;
  size_t base = (size_t)row * DD + lane * 8;
  const float4* o4 = (const float4*)(O + base);
  const float4* q4 = (const float4*)(qin + base);
  float4 a = o4[0], b2 = o4[1], c = q4[0], d2 = q4[1];
  float v[8];
  v[0] = a.x + c.x; v[1] = a.y + c.y; v[2] = a.z + c.z; v[3] = a.w + c.w;
  v[4] = b2.x + d2.x; v[5] = b2.y + d2.y; v[6] = b2.z + d2.z; v[7] = b2.w + d2.w;
  float s = 0.f, s2 = 0.f;
#pragma unroll
  for (int j = 0; j < 8; ++j) { s += v[j]; s2 += v[j] * v[j]; }
#pragma unroll
  for (int xm = 1; xm < 64; xm <<= 1) {
    s += __shfl_xor(s, xm);
    s2 += __shfl_xor(s2, xm);
  }
  float mu = s * (1.0f / DD);
  float var = s2 * (1.0f / DD) - mu * mu;
  float rs = rsqrtf(var + 1e-3f);
  const float* g = gamma + lane * 8;
  const float* bb = beta + lane * 8;
  float* ob = out + base;
#pragma unroll
  for (int j = 0; j < 8; ++j) ob[j] = (v[j] - mu) * rs * g[j] + bb[j];
}

// ---------------- launch ----------------
extern "C" void kernel_launch(void* const* d_in, const int* in_sizes, int n_in,
                              void* d_out, int out_size, void* d_ws, size_t ws_size,
                              hipStream_t stream) {
  (void)in_sizes; (void)n_in; (void)out_size; (void)ws_size;
  const float* queries = (const float*)d_in[0];
  const float* keys_in = (const float*)d_in[1];
  const float* Wq = (const float*)d_in[2];
  const float* bq = (const float*)d_in[3];
  const float* Wk = (const float*)d_in[4];
  const float* bk = (const float*)d_in[5];
  const float* Wv = (const float*)d_in[6];
  const float* bv = (const float*)d_in[7];
  const float* gamma = (const float*)d_in[8];
  const float* beta  = (const float*)d_in[9];
  float* out = (float*)d_out;

  char* ws = (char*)d_ws;
  unsigned short* qb = (unsigned short*)(ws);
  unsigned short* kb = (unsigned short*)(ws + (8ull << 20));
  float*          O  = (float*)(ws);               // aliases qb/kb after gemm
  unsigned short* Qp = (unsigned short*)(ws + (16ull << 20));
  unsigned short* Kp = (unsigned short*)(ws + (24ull << 20));
  unsigned short* Vp = (unsigned short*)(ws + (32ull << 20));
  unsigned short* Vt = (unsigned short*)(ws + (40ull << 20));
  unsigned short* Wt = (unsigned short*)(ws + (48ull << 20));
  float* qmaskp = (float*)(ws + (50ull << 20));
  uint2* kbitsp = (uint2*)(ws + (50ull << 20) + (512ull << 10));

  cvt_inputs<<<4096, 256, 0, stream>>>((const float4*)queries, (const float4*)keys_in,
                                       (us4*)qb, (us4*)kb);
  cvt_w<<<dim3(16, 16, 3), 256, 0, stream>>>(Wq, Wk, Wv, Wt);
  gemm_proj<<<dim3(64, 4, 3), 256, 0, stream>>>(qb, kb, Wt, bq, bk, bv, Qp, Kp, Vp);
  transpose_v<<<dim3(32, 8, 4), 256, 0, stream>>>(Vp, Vt);
  mask_kernel<<<512, 256, 0, stream>>>(Qp, Kp, qmaskp, kbitsp);
  attn_kernel<<<512, 256, 0, stream>>>(Qp, Kp, Vt, kbitsp, qmaskp, O);
  ln_kernel<<<2048, 256, 0, stream>>>(O, queries, gamma, beta, out);
}

// Round 3
// 193.840 us; speedup vs baseline: 1.3096x; 1.3096x over previous
//
#include <hip/hip_runtime.h>
#include <cstdint>

// Problem constants
#define BB 4
#define TT 2048      // TQ == TK
#define DD 512
#define HH 8
#define DH 64
#define NT (TT / 64) // KV tiles of 64

using bf16x8 = __attribute__((ext_vector_type(8))) __bf16;
using f32x4  = __attribute__((ext_vector_type(4))) float;
using f32x16 = __attribute__((ext_vector_type(16))) float;
using us8    = __attribute__((ext_vector_type(8))) unsigned short;
using us4    = __attribute__((ext_vector_type(4))) unsigned short;
using u32x2  = __attribute__((ext_vector_type(2))) unsigned int;

typedef const __attribute__((address_space(1))) unsigned int* as1cp;
typedef __attribute__((address_space(3))) unsigned int* as3p;

__device__ __forceinline__ void gload16(const void* g, void* l) {
  __builtin_amdgcn_global_load_lds((as1cp)(uintptr_t)g,
                                   (as3p)(unsigned int)(uintptr_t)l, 16, 0, 0);
}

__device__ __forceinline__ unsigned short f2bf(float x) {
  unsigned int u = __float_as_uint(x);
  u += 0x7fffu + ((u >> 16) & 1u);
  return (unsigned short)(u >> 16);
}
__device__ __forceinline__ float bf2f(unsigned short u) {
  return __uint_as_float(((unsigned int)u) << 16);
}
__device__ __forceinline__ f32x4 MFMA(bf16x8 a, bf16x8 b, f32x4 c) {
  return __builtin_amdgcn_mfma_f32_16x16x32_bf16(a, b, c, 0, 0, 0);
}
__device__ __forceinline__ f32x16 MFMA32(bf16x8 a, bf16x8 b, f32x16 c) {
  return __builtin_amdgcn_mfma_f32_32x32x16_bf16(a, b, c, 0, 0, 0);
}
// v_cvt_pk_bf16_f32: dst[15:0]=bf16(lo), dst[31:16]=bf16(hi)
__device__ __forceinline__ unsigned int cvtpk(float lo, float hi) {
  unsigned int r;
  asm("v_cvt_pk_bf16_f32 %0, %1, %2" : "=v"(r) : "v"(lo), "v"(hi));
  return r;
}

#define WAITVM(N) asm volatile("s_waitcnt vmcnt(" #N ")" ::: "memory")
#define RAWBAR() asm volatile("s_barrier" ::: "memory")

// ---------------- 1. convert inputs to bf16 ----------------
__global__ __launch_bounds__(256) void cvt_inputs(const float4* __restrict__ q,
                                                  const float4* __restrict__ k,
                                                  us4* __restrict__ qb,
                                                  us4* __restrict__ kb) {
  size_t i = (size_t)blockIdx.x * 256 + threadIdx.x;
  float4 a = q[i];
  us4 o; o[0] = f2bf(a.x); o[1] = f2bf(a.y); o[2] = f2bf(a.z); o[3] = f2bf(a.w);
  qb[i] = o;
  float4 b = k[i];
  us4 p; p[0] = f2bf(b.x); p[1] = f2bf(b.y); p[2] = f2bf(b.z); p[3] = f2bf(b.w);
  kb[i] = p;
}

// ---------------- 2. weight transpose + convert ----------------
__global__ __launch_bounds__(256) void cvt_w(const float* __restrict__ Wq,
                                             const float* __restrict__ Wk,
                                             const float* __restrict__ Wv,
                                             unsigned short* __restrict__ Wt) {
  __shared__ float tile[32][33];
  int z = blockIdx.z;
  const float* W = (z == 0) ? Wq : (z == 1) ? Wk : Wv;
  int k0 = blockIdx.x * 32, n0 = blockIdx.y * 32;
  int r = threadIdx.x >> 5, c = threadIdx.x & 31;
#pragma unroll
  for (int p = 0; p < 4; ++p)
    tile[r + p * 8][c] = W[(size_t)(k0 + r + p * 8) * DD + n0 + c];
  __syncthreads();
  unsigned short* o = Wt + (size_t)z * DD * DD;
#pragma unroll
  for (int p = 0; p < 4; ++p)
    o[(size_t)(n0 + r + p * 8) * DD + k0 + c] = f2bf(tile[c][r + p * 8]);
}

// ---------------- 3. projection GEMM: out = relu(A @ W + b) [* 0.125 for Q] ----------------
__global__ __launch_bounds__(256) void gemm_proj(const unsigned short* __restrict__ qb,
                                                 const unsigned short* __restrict__ kb,
                                                 const unsigned short* __restrict__ Wt,
                                                 const float* __restrict__ bq,
                                                 const float* __restrict__ bk,
                                                 const float* __restrict__ bv,
                                                 unsigned short* __restrict__ Qp,
                                                 unsigned short* __restrict__ Kp,
                                                 unsigned short* __restrict__ Vp) {
  int z = blockIdx.z;
  const unsigned short* A  = (z == 0) ? qb : kb;
  const unsigned short* Bt = Wt + (size_t)z * DD * DD;
  const float* bias = (z == 0) ? bq : (z == 1) ? bk : bv;
  unsigned short* out = (z == 0) ? Qp : (z == 1) ? Kp : Vp;
  const float osc = (z == 0) ? 0.125f : 1.0f;   // fold 1/sqrt(dh) into Q

  __shared__ __align__(16) unsigned short As[128 * 32];
  __shared__ __align__(16) unsigned short Bs[128 * 32];

  int mb = blockIdx.x * 128, nb = blockIdx.y * 128;
  int w = threadIdx.x >> 6, lane = threadIdx.x & 63;
  int l15 = lane & 15, lg = lane >> 4;
  int wr = (w >> 1) * 64, wc = (w & 1) * 64;

  f32x4 acc[4][4] = {};

  for (int kt = 0; kt < DD / 32; ++kt) {
    int kk = kt * 32;
    int t = threadIdx.x;
#pragma unroll
    for (int it = 0; it < 2; ++it) {
      int c = t + it * 256;
      gload16(A  + (size_t)(mb + (c >> 2)) * DD + kk + (c & 3) * 8, As + c * 8);
      gload16(Bt + (size_t)(nb + (c >> 2)) * DD + kk + (c & 3) * 8, Bs + c * 8);
    }
    __syncthreads();
    bf16x8 af[4], bf[4];
#pragma unroll
    for (int m = 0; m < 4; ++m)
      af[m] = *(const bf16x8*)&As[(wr + m * 16 + l15) * 32 + lg * 8];
#pragma unroll
    for (int n = 0; n < 4; ++n)
      bf[n] = *(const bf16x8*)&Bs[(wc + n * 16 + l15) * 32 + lg * 8];
#pragma unroll
    for (int m = 0; m < 4; ++m)
#pragma unroll
      for (int n = 0; n < 4; ++n)
        acc[m][n] = MFMA(af[m], bf[n], acc[m][n]);
    __syncthreads();
  }

#pragma unroll
  for (int m = 0; m < 4; ++m)
#pragma unroll
    for (int n = 0; n < 4; ++n)
#pragma unroll
      for (int i = 0; i < 4; ++i) {
        int row = mb + wr + m * 16 + lg * 4 + i;
        int col = nb + wc + n * 16 + l15;
        float v = acc[m][n][i] + bias[col];
        out[(size_t)row * DD + col] = f2bf(fmaxf(v, 0.f) * osc);
      }
}

// ---------------- 4. V transpose: Vp[B*TK, D] -> Vt[B, D, TK] ----------------
__global__ __launch_bounds__(256) void transpose_v(const unsigned short* __restrict__ Vp,
                                                   unsigned short* __restrict__ Vt) {
  __shared__ unsigned short tile[64][72];
  int b = blockIdx.z, k0 = blockIdx.x * 64, d0 = blockIdx.y * 64;
  int t = threadIdx.x;
  int r = t >> 3, c8 = (t & 7) * 8;
#pragma unroll
  for (int p = 0; p < 2; ++p) {
    int row = r + p * 32;
    us8 v = *(const us8*)&Vp[(size_t)(b * TT + k0 + row) * DD + d0 + c8];
#pragma unroll
    for (int j = 0; j < 8; ++j) tile[row][c8 + j] = v[j];
  }
  __syncthreads();
#pragma unroll
  for (int p = 0; p < 2; ++p) {
    int dr = r + p * 32;
    us8 o;
#pragma unroll
    for (int j = 0; j < 8; ++j) o[j] = tile[c8 + j][dr];
    *(us8*)&Vt[((size_t)b * DD + d0 + dr) * TT + k0 + c8] = o;
  }
}

// ---------------- 5. masks: qmask float [B*H][TT]; kmask as bitwords uint2 per tile-64 ----------------
__global__ __launch_bounds__(256) void mask_kernel(const unsigned short* __restrict__ Qp,
                                                   const unsigned short* __restrict__ Kp,
                                                   float* __restrict__ qmask,
                                                   uint2* __restrict__ kbits) {
  int id = blockIdx.x * 4 + (threadIdx.x >> 6);   // [0, 2048) waves
  int lane = threadIdx.x & 63;
  int side = id >> 10;            // 0 = Q, 1 = K
  int rem = id & 1023;
  int bh = rem >> 5, tile = rem & 31;
  int b = bh >> 3, h = bh & 7;
  const unsigned short* src =
      (side ? Kp : Qp) + ((size_t)(b * TT + tile * 64 + lane)) * DD + h * DH;
  float s = 0.f;
#pragma unroll
  for (int j = 0; j < 64; j += 8) {
    us8 v = *(const us8*)(src + j);
#pragma unroll
    for (int e = 0; e < 8; ++e) s += bf2f(v[e]);
  }
  if (side == 0) {
    qmask[(size_t)bh * TT + tile * 64 + lane] = (s > 0.f) ? 1.f : 0.f;
  } else {
    unsigned long long mb = __ballot(s > 0.f);
    if (lane == 0)
      kbits[bh * NT + tile] = make_uint2((unsigned int)mb, (unsigned int)(mb >> 32));
  }
}

// ---------------- 6. flash attention (LDS-staged tiles, in-register softmax) ----------------
// Per wave: 32 q-rows. S^T = mfma(Kfrag, Qfrag) -> lane holds P[.][qrow=lane&31].
// O^T = mfma(Vtfrag, Pfrag) -> col stays qrow: m/l/alpha/qmask all lane-local.
// K/V tiles staged via global_load_lds (coalesced), double-buffered, counted vmcnt.
#define PV_SLOT(SS, base, ks)                                               \
  {                                                                         \
    unsigned int w0_ = cvtpk(SS[(base) + 0], SS[(base) + 1]);               \
    unsigned int w1_ = cvtpk(SS[(base) + 2], SS[(base) + 3]);               \
    unsigned int w2_ = cvtpk(SS[(base) + 4], SS[(base) + 5]);               \
    unsigned int w3_ = cvtpk(SS[(base) + 6], SS[(base) + 7]);               \
    u32x2 r20_ = __builtin_amdgcn_permlane32_swap(w2_, w0_, false, false);  \
    u32x2 r31_ = __builtin_amdgcn_permlane32_swap(w3_, w1_, false, false);  \
    union { unsigned int u[4]; bf16x8 v; } pa_;                             \
    pa_.u[0] = r20_[1]; pa_.u[1] = r31_[1];                                 \
    pa_.u[2] = r20_[0]; pa_.u[3] = r31_[0];                                 \
    oat0 = MFMA32(vf0[(ks)], pa_.v, oat0);                                  \
    oat1 = MFMA32(vf1[(ks)], pa_.v, oat1);                                  \
  }

// stage tile tt (64 kpos) of K and V^T into LDS buffer pb; source pre-swizzled
// (rule #21): LDS chunk c holds logical chunk (c&7)^(r&7) of row r=c>>3.
#define STAGE(tt, pb)                                                        \
  {                                                                          \
    int c0_ = threadIdx.x;                                                   \
    _Pragma("unroll")                                                        \
    for (int it_ = 0; it_ < 2; ++it_) {                                      \
      int c_ = c0_ + it_ * 256;                                              \
      int r_ = c_ >> 3, j_ = c_ & 7;                                         \
      int js_ = j_ ^ (r_ & 7);                                               \
      gload16(kg + (size_t)((tt) * 64 + r_) * DD + js_ * 8,                  \
              &KsBuf[pb][(size_t)c_ * 8]);                                   \
      gload16(vg + (size_t)r_ * TT + (tt) * 64 + js_ * 8,                    \
              &VsBuf[pb][(size_t)c_ * 8]);                                   \
    }                                                                        \
  }

__global__ __launch_bounds__(256) void attn_kernel(
    const unsigned short* __restrict__ Qp,
    const unsigned short* __restrict__ Kp,
    const unsigned short* __restrict__ Vt,
    const uint2* __restrict__ kbits,
    const float* __restrict__ qmask,
    float* __restrict__ O) {
  __shared__ __align__(16) unsigned short KsBuf[2][64 * 64];
  __shared__ __align__(16) unsigned short VsBuf[2][64 * 64];

  const int w = threadIdx.x >> 6;
  const int lane = threadIdx.x & 63;
  const int l31 = lane & 31, h2 = lane >> 5;

  // XCD-bijective swizzle: 512 blocks -> each (b,h)'s 16 q-tiles on one XCD
  int flat = blockIdx.x;
  int wg = (flat & 7) * 64 + (flat >> 3);
  int qt = wg & 15, bh = wg >> 4;
  int h = bh & 7, b = bh >> 3;
  int q0 = qt * 128 + w * 32;

  const unsigned short* qbase =
      Qp + ((size_t)(b * TT + q0 + l31)) * DD + h * DH + h2 * 8;
  bf16x8 qf[4];
#pragma unroll
  for (int kd = 0; kd < 4; ++kd) qf[kd] = *(const bf16x8*)(qbase + kd * 16);

  const unsigned short* kg = Kp + ((size_t)b * TT) * DD + h * DH;
  const unsigned short* vg = Vt + ((size_t)(b * DD + h * DH)) * TT;
  const uint2* kb_ptr = kbits + (size_t)bh * NT;

  f32x16 oat0 = {}, oat1 = {};
  float m_i = -1e30f, l_i = 0.f;

  STAGE(0, 0);

  for (int t = 0; t < NT; ++t) {
    int pb = t & 1;
    if (t + 1 < NT) {
      STAGE(t + 1, pb ^ 1);
      WAITVM(4);          // wait tile t's 4 loads; t+1's stay in flight
    } else {
      WAITVM(0);
    }
    RAWBAR();

    const unsigned short* ksb = &KsBuf[pb][0];
    const unsigned short* vsb = &VsBuf[pb][0];

    // K fragments (swizzled ds_read_b128)
    bf16x8 kf0[4], kf1[4];
#pragma unroll
    for (int kd = 0; kd < 4; ++kd) {
      int j = kd * 2 + h2;
      int r0 = l31, r1 = 32 + l31;
      kf0[kd] = *(const bf16x8*)&ksb[((size_t)r0 * 8 + (j ^ (r0 & 7))) * 8];
      kf1[kd] = *(const bf16x8*)&ksb[((size_t)r1 * 8 + (j ^ (r1 & 7))) * 8];
    }

    // S^T = K . Q^T
    f32x16 s0 = {}, s1 = {};
    __builtin_amdgcn_s_setprio(1);
#pragma unroll
    for (int kd = 0; kd < 4; ++kd) s0 = MFMA32(kf0[kd], qf[kd], s0);
#pragma unroll
    for (int kd = 0; kd < 4; ++kd) s1 = MFMA32(kf1[kd], qf[kd], s1);
    __builtin_amdgcn_s_setprio(0);

    // V fragments (issue early; consumed after softmax)
    bf16x8 vf0[4], vf1[4];
#pragma unroll
    for (int ks = 0; ks < 4; ++ks) {
      int j = ks * 2 + h2;
      int r0 = l31, r1 = 32 + l31;
      vf0[ks] = *(const bf16x8*)&vsb[((size_t)r0 * 8 + (j ^ (r0 & 7))) * 8];
      vf1[ks] = *(const bf16x8*)&vsb[((size_t)r1 * 8 + (j ^ (r1 & 7))) * 8];
    }

    // key mask (fast path: all ones)
    uint2 kw = kb_ptr[t];
    if ((kw.x & kw.y) != 0xffffffffu) {
      unsigned int w0s = kw.x >> (h2 * 4), w1s = kw.y >> (h2 * 4);
#pragma unroll
      for (int r = 0; r < 16; ++r) {
        int bi = (r & 3) + 8 * (r >> 2);
        if (!((w0s >> bi) & 1)) s0[r] = -1e30f;
        if (!((w1s >> bi) & 1)) s1[r] = -1e30f;
      }
    }

    // row max (own 32) + cross-half combine
    float x0 = fmaxf(fmaxf(fmaxf(s0[0], s0[1]), fmaxf(s0[2], s0[3])),
                     fmaxf(fmaxf(s0[4], s0[5]), fmaxf(s0[6], s0[7])));
    float x1 = fmaxf(fmaxf(fmaxf(s0[8], s0[9]), fmaxf(s0[10], s0[11])),
                     fmaxf(fmaxf(s0[12], s0[13]), fmaxf(s0[14], s0[15])));
    float x2 = fmaxf(fmaxf(fmaxf(s1[0], s1[1]), fmaxf(s1[2], s1[3])),
                     fmaxf(fmaxf(s1[4], s1[5]), fmaxf(s1[6], s1[7])));
    float x3 = fmaxf(fmaxf(fmaxf(s1[8], s1[9]), fmaxf(s1[10], s1[11])),
                     fmaxf(fmaxf(s1[12], s1[13]), fmaxf(s1[14], s1[15])));
    float pm = fmaxf(fmaxf(x0, x1), fmaxf(x2, x3));
    u32x2 sw = __builtin_amdgcn_permlane32_swap(__float_as_uint(pm),
                                                __float_as_uint(pm), false, false);
    pm = fmaxf(__uint_as_float(sw[0]), __uint_as_float(sw[1]));

    // defer-max: rescale only when max grew by > 8
    if (__any(pm > m_i + 8.f)) {
      float mn = fmaxf(m_i, pm);
      float al = __expf(m_i - mn);
      m_i = mn;
      l_i *= al;
#pragma unroll
      for (int r = 0; r < 16; ++r) { oat0[r] *= al; oat1[r] *= al; }
    }

    // p = exp(s - m), row sum
    float a0 = 0.f, a1 = 0.f, a2 = 0.f, a3 = 0.f;
#pragma unroll
    for (int r = 0; r < 8; ++r)  { float p = __expf(s0[r] - m_i); s0[r] = p; a0 += p; }
#pragma unroll
    for (int r = 8; r < 16; ++r) { float p = __expf(s0[r] - m_i); s0[r] = p; a1 += p; }
#pragma unroll
    for (int r = 0; r < 8; ++r)  { float p = __expf(s1[r] - m_i); s1[r] = p; a2 += p; }
#pragma unroll
    for (int r = 8; r < 16; ++r) { float p = __expf(s1[r] - m_i); s1[r] = p; a3 += p; }
    float rs = (a0 + a1) + (a2 + a3);
    u32x2 sr = __builtin_amdgcn_permlane32_swap(__float_as_uint(rs),
                                                __float_as_uint(rs), false, false);
    rs = __uint_as_float(sr[0]) + __uint_as_float(sr[1]);
    l_i += rs;

    // O^T += Vt . P : pack P to bf16 in-register (cvt_pk + permlane32_swap)
    __builtin_amdgcn_s_setprio(1);
    PV_SLOT(s0, 0, 0)
    PV_SLOT(s0, 8, 1)
    PV_SLOT(s1, 0, 2)
    PV_SLOT(s1, 8, 3)
    __builtin_amdgcn_s_setprio(0);

    if (t + 1 < NT) RAWBAR();   // all waves done reading buf[pb] before overwrite
  }

  // epilogue: all lane-local. oat reg r -> d = (r&3) + 8*(r>>2) + 4*h2 (+32 for oat1)
  float qm = qmask[(size_t)bh * TT + q0 + l31];
  float sc = qm / l_i;
  float* ob = O + ((size_t)(b * TT + q0 + l31)) * DD + h * DH + h2 * 4;
#pragma unroll
  for (int qq = 0; qq < 4; ++qq) {
    float4 v0 = make_float4(oat0[4 * qq + 0] * sc, oat0[4 * qq + 1] * sc,
                            oat0[4 * qq + 2] * sc, oat0[4 * qq + 3] * sc);
    *(float4*)(ob + 8 * qq) = v0;
    float4 v1 = make_float4(oat1[4 * qq + 0] * sc, oat1[4 * qq + 1] * sc,
                            oat1[4 * qq + 2] * sc, oat1[4 * qq + 3] * sc);
    *(float4*)(ob + 32 + 8 * qq) = v1;
  }
}

// ---------------- 7. residual + LayerNorm ----------------
__global__ __launch_bounds__(256) void ln_kernel(const float* __restrict__ O,
                                                 const float* __restrict__ qin,
                                                 const float* __restrict__ gamma,
                                                 const float* __restrict__ beta,
                                                 float* __restrict__ out) {
  int row = blockIdx.x * 4 + (threadIdx.x >> 6);
  int lane = threadIdx.x & 63;
  size_t base = (size_t)row * DD + lane * 8;
  const float4* o4 = (const float4*)(O + base);
  const float4* q4 = (const float4*)(qin + base);
  float4 a = o4[0], b2 = o4[1], c = q4[0], d2 = q4[1];
  float v[8];
  v[0] = a.x + c.x; v[1] = a.y + c.y; v[2] = a.z + c.z; v[3] = a.w + c.w;
  v[4] = b2.x + d2.x; v[5] = b2.y + d2.y; v[6] = b2.z + d2.z; v[7] = b2.w + d2.w;
  float s = 0.f, s2 = 0.f;
#pragma unroll
  for (int j = 0; j < 8; ++j) { s += v[j]; s2 += v[j] * v[j]; }
#pragma unroll
  for (int xm = 1; xm < 64; xm <<= 1) {
    s += __shfl_xor(s, xm);
    s2 += __shfl_xor(s2, xm);
  }
  float mu = s * (1.0f / DD);
  float var = s2 * (1.0f / DD) - mu * mu;
  float rs = rsqrtf(var + 1e-3f);
  const float* g = gamma + lane * 8;
  const float* bb = beta + lane * 8;
  float* ob = out + base;
#pragma unroll
  for (int j = 0; j < 8; ++j) ob[j] = (v[j] - mu) * rs * g[j] + bb[j];
}

// ---------------- launch ----------------
extern "C" void kernel_launch(void* const* d_in, const int* in_sizes, int n_in,
                              void* d_out, int out_size, void* d_ws, size_t ws_size,
                              hipStream_t stream) {
  (void)in_sizes; (void)n_in; (void)out_size; (void)ws_size;
  const float* queries = (const float*)d_in[0];
  const float* keys_in = (const float*)d_in[1];
  const float* Wq = (const float*)d_in[2];
  const float* bq = (const float*)d_in[3];
  const float* Wk = (const float*)d_in[4];
  const float* bk = (const float*)d_in[5];
  const float* Wv = (const float*)d_in[6];
  const float* bv = (const float*)d_in[7];
  const float* gamma = (const float*)d_in[8];
  const float* beta  = (const float*)d_in[9];
  float* out = (float*)d_out;

  char* ws = (char*)d_ws;
  unsigned short* qb = (unsigned short*)(ws);
  unsigned short* kb = (unsigned short*)(ws + (8ull << 20));
  float*          O  = (float*)(ws);               // aliases qb/kb after gemm
  unsigned short* Qp = (unsigned short*)(ws + (16ull << 20));
  unsigned short* Kp = (unsigned short*)(ws + (24ull << 20));
  unsigned short* Vp = (unsigned short*)(ws + (32ull << 20));
  unsigned short* Vt = (unsigned short*)(ws + (40ull << 20));
  unsigned short* Wt = (unsigned short*)(ws + (48ull << 20));
  float* qmaskp = (float*)(ws + (50ull << 20));
  uint2* kbitsp = (uint2*)(ws + (50ull << 20) + (512ull << 10));

  cvt_inputs<<<4096, 256, 0, stream>>>((const float4*)queries, (const float4*)keys_in,
                                       (us4*)qb, (us4*)kb);
  cvt_w<<<dim3(16, 16, 3), 256, 0, stream>>>(Wq, Wk, Wv, Wt);
  gemm_proj<<<dim3(64, 4, 3), 256, 0, stream>>>(qb, kb, Wt, bq, bk, bv, Qp, Kp, Vp);
  transpose_v<<<dim3(32, 8, 4), 256, 0, stream>>>(Vp, Vt);
  mask_kernel<<<512, 256, 0, stream>>>(Qp, Kp, qmaskp, kbitsp);
  attn_kernel<<<512, 256, 0, stream>>>(Qp, Kp, Vt, kbitsp, qmaskp, O);
  ln_kernel<<<2048, 256, 0, stream>>>(O, queries, gamma, beta, out);
}